// Round 5
// baseline (38.996 us; speedup 1.0000x reference)
//
#include <hip/hip_runtime.h>

// GSplat renderer, separable-Gaussian formulation, 3 kernels:
//  1) gs_tables: exG[n][w]=exp2(K dx^2), eyG[n][h]=exp2(K dy^2),
//     colpack[n]=op*(r,g,b,1).
//  2) gs_accum: wave = 64 cols x 8 rows, per-thread acc[8][4]. The ex loads
//     are hand-pipelined at distance 2 (banks exa/exb + prefetch) so ~640cy
//     of L2 latency hides under ~660cy of FMA work — the compiler does NOT
//     rotate loads across iterations on its own (R3/R4 lesson).
//  3) gs_finalize: sum 16 parts, divide, clip.

constexpr int HH = 256;
constexpr int WW = 256;
constexpr int PIX = HH * WW;
constexpr float COORD_STEP = 2.0f / 255.0f;  // linspace(-1,1,256) step

__global__ __launch_bounds__(256) void gs_tables(
    const float* __restrict__ means, const float* __restrict__ scales,
    const float* __restrict__ opac, const float* __restrict__ colors,
    float* __restrict__ exG, float* __restrict__ eyG,
    float4* __restrict__ colpack) {
  int n = blockIdx.x;
  int t = threadIdx.x;
  float mx = means[3 * n + 0], my = means[3 * n + 1], mz = means[3 * n + 2];
  float scl = fmaxf((scales[3 * n + 0] + scales[3 * n + 1] + scales[3 * n + 2]) * (1.0f / 3.0f), 1e-4f);
  float op = opac[n];
  float zs = fabsf(mz) + 1.0f;
  float rzs = 1.0f / zs;
  float px = tanhf(mx * rzs);
  float py = tanhf(my * rzs);
  float sigma = fminf(fmaxf(scl * rzs, 0.02f), 0.5f);
  float inv_s = 1.0f / sigma;
  float K = -0.72134752044f * inv_s * inv_s;  // -0.5/ln2 * inv_s^2
  float c = -1.0f + COORD_STEP * (float)t;
  float dx = c - px;
  exG[n * WW + t] = exp2f(K * dx * dx);
  float dy = c - py;
  eyG[n * HH + t] = exp2f(K * dy * dy);
  if (t == 0) {
    colpack[n] = make_float4(op * colors[3 * n + 0], op * colors[3 * n + 1],
                             op * colors[3 * n + 2], op);
  }
}

// grid = (WW/64, HH/32, parts); block = 256 = 4 waves.
// Wave rq: rows [by*32 + rq*8, +8), cols [bx*64, +64).
__global__ __launch_bounds__(256) void gs_accum(
    const float* __restrict__ exG, const float* __restrict__ eyG,
    const float4* __restrict__ colpack, float* __restrict__ partials,
    int nchunk) {
  int col = (blockIdx.x << 6) + (threadIdx.x & 63);
  int rq = __builtin_amdgcn_readfirstlane(threadIdx.x >> 6);  // wave id 0..3
  int row0 = (blockIdx.y << 5) + (rq << 3);
  int part = blockIdx.z;
  int n0 = part * nchunk;

  const float* exp_ptr = exG + (size_t)n0 * WW + col;
  const float* eyp = eyG + (size_t)n0 * HH + row0;  // wave-uniform
  const float4* cp = colpack + n0;                  // wave-uniform

  float acc[8][4] = {{0.f}};

  // Distance-2 pipeline banks for the ex column values.
  float exa0 = exp_ptr[0 * WW], exa1 = exp_ptr[1 * WW],
        exa2 = exp_ptr[2 * WW], exa3 = exp_ptr[3 * WW];
  float exb0 = exp_ptr[4 * WW], exb1 = exp_ptr[5 * WW],
        exb2 = exp_ptr[6 * WW], exb3 = exp_ptr[7 * WW];
  const float* pre_ptr = exp_ptr + 8 * WW;  // prefetch cursor (group i+8)
  // NOTE: pre_ptr over-reads up to 8 rows past this part's chunk at the tail;
  // that lands in the next chunk / eyG region of the workspace — in-bounds,
  // loaded but never used.

#pragma unroll 1
  for (int i = 0; i < nchunk; i += 4) {
    float p0 = pre_ptr[0 * WW];
    float p1 = pre_ptr[1 * WW];
    float p2 = pre_ptr[2 * WW];
    float p3 = pre_ptr[3 * WW];
#define GS_N(J, EX)                                     \
    {                                                   \
      const float* ey = eyp + (J) * HH;                 \
      float4 cc = cp[J];                                \
      _Pragma("unroll")                                 \
      for (int r = 0; r < 8; ++r) {                     \
        float wt = ey[r] * (EX);                        \
        acc[r][0] = fmaf(wt, cc.x, acc[r][0]);          \
        acc[r][1] = fmaf(wt, cc.y, acc[r][1]);          \
        acc[r][2] = fmaf(wt, cc.z, acc[r][2]);          \
        acc[r][3] = fmaf(wt, cc.w, acc[r][3]);          \
      }                                                 \
    }
    GS_N(0, exa0)
    GS_N(1, exa1)
    GS_N(2, exa2)
    GS_N(3, exa3)
#undef GS_N
    exa0 = exb0; exa1 = exb1; exa2 = exb2; exa3 = exb3;
    exb0 = p0;   exb1 = p1;   exb2 = p2;   exb3 = p3;
    pre_ptr += 4 * WW;
    eyp += 4 * HH;
    cp += 4;
  }

  float* pb = partials + (size_t)part * 4 * PIX + col;
#pragma unroll
  for (int r = 0; r < 8; ++r) {
#pragma unroll
    for (int c = 0; c < 4; ++c) {
      pb[c * PIX + (row0 + r) * WW] = acc[r][c];
    }
  }
}

// grid = (PIX/4/256, 3); each thread: one float4-group of one channel.
__global__ __launch_bounds__(256) void gs_finalize(
    const float4* __restrict__ partials4, float4* __restrict__ out4,
    int parts) {
  int g = blockIdx.x * 256 + threadIdx.x;  // 0..PIX/4-1
  int ch = blockIdx.y;                     // 0..2
  float nx = 0.f, ny = 0.f, nz = 0.f, nw = 0.f;
  float dx = 0.f, dy = 0.f, dz = 0.f, dw = 0.f;
  const float4* np = partials4 + (size_t)ch * (PIX / 4) + g;
  const float4* dp = partials4 + (size_t)3 * (PIX / 4) + g;
#pragma unroll 4
  for (int p = 0; p < parts; ++p) {
    float4 a = *np;
    float4 b = *dp;
    nx += a.x; ny += a.y; nz += a.z; nw += a.w;
    dx += b.x; dy += b.y; dz += b.z; dw += b.w;
    np += 4 * (PIX / 4);
    dp += 4 * (PIX / 4);
  }
  float4 o;
  o.x = fminf(fmaxf(nx / fmaxf(dx, 1e-5f), 0.0f), 1.0f);
  o.y = fminf(fmaxf(ny / fmaxf(dy, 1e-5f), 0.0f), 1.0f);
  o.z = fminf(fmaxf(nz / fmaxf(dz, 1e-5f), 0.0f), 1.0f);
  o.w = fminf(fmaxf(nw / fmaxf(dw, 1e-5f), 0.0f), 1.0f);
  out4[(size_t)ch * (PIX / 4) + g] = o;
}

extern "C" void kernel_launch(void* const* d_in, const int* in_sizes, int n_in,
                              void* d_out, int out_size, void* d_ws, size_t ws_size,
                              hipStream_t stream) {
  const float* means = (const float*)d_in[0];
  // d_in[1] = quats (unused by reference)
  const float* scales = (const float*)d_in[2];
  const float* opac = (const float*)d_in[3];
  const float* colors = (const float*)d_in[4];
  float* out = (float*)d_out;
  int N = in_sizes[0] / 3;  // 2048

  // Workspace layout (16B-aligned):
  //   exG      [N][WW] float
  //   eyG      [N][HH] float
  //   colpack  [N] float4
  //   partials [parts][4][PIX] float
  char* ws = (char*)d_ws;
  float* exG = (float*)ws;
  float* eyG = (float*)(ws + (size_t)N * WW * 4);
  float4* colpack = (float4*)(ws + (size_t)N * (WW + HH) * 4);
  size_t base = (size_t)N * (WW + HH) * 4 + (size_t)N * 16;
  float* partials = (float*)(ws + base);

  // Largest power-of-2 parts (<=16) whose partial planes fit the workspace.
  int parts = 1;
  for (int p = 16; p >= 1; p >>= 1) {
    if (base + (size_t)p * 4 * PIX * 4 <= ws_size) { parts = p; break; }
  }
  int nchunk = N / parts;

  gs_tables<<<N, 256, 0, stream>>>(means, scales, opac, colors, exG, eyG, colpack);
  gs_accum<<<dim3(WW / 64, HH / 32, parts), 256, 0, stream>>>(
      exG, eyG, colpack, partials, nchunk);
  gs_finalize<<<dim3(PIX / 4 / 256, 3), 256, 0, stream>>>(
      (const float4*)partials, (float4*)out, parts);
}

// Round 7
// 35.834 us; speedup vs baseline: 1.0883x; 1.0883x over previous
//
#include <hip/hip_runtime.h>

// GSplat renderer, separable-Gaussian, fully-fused LDS formulation.
// Block = (64 cols x 32 rows) x one 128-gaussian chunk.
// Prologue (per block): params -> LDS; exL[n][col]=exp2(K dx^2),
// eyL[n][row]=exp2(K dy^2), colL[n]=op*(r,g,b,1) -> LDS.
// Main loop: pure LDS reads + FMA. No global/scalar loads in the hot loop
// (R5 lesson: per-iteration s_loads force lgkmcnt(0) serialization).
// Epilogue: per-part partial planes (no atomics); gs_finalize reduces.
// R6 bug fixed: exL fill must use the block's absolute column (bx*64+lane),
// not lane alone.

constexpr int HH = 256;
constexpr int WW = 256;
constexpr int PIX = HH * WW;
constexpr int NCHUNK = 128;  // gaussians per block
constexpr float COORD_STEP = 2.0f / 255.0f;  // linspace(-1,1,256) step

__global__ __launch_bounds__(256) void gs_accum(
    const float* __restrict__ means, const float* __restrict__ scales,
    const float* __restrict__ opac, const float* __restrict__ colors,
    float* __restrict__ partials) {
  __shared__ float pxL[NCHUNK], pyL[NCHUNK], kL[NCHUNK];
  __shared__ float4 colL[NCHUNK];
  __shared__ float exL[NCHUNK][64];   // 32 KB
  __shared__ float eyL[NCHUNK][32];   // 16 KB

  const int t = threadIdx.x;
  const int lane = t & 63;
  const int rq = __builtin_amdgcn_readfirstlane(t >> 6);  // wave id 0..3
  const int col = (blockIdx.x << 6) + lane;
  const int row0 = (blockIdx.y << 5) + (rq << 3);
  const int n0 = blockIdx.z * NCHUNK;

  // --- params for this chunk (threads 0..127, one gaussian each) ---
  if (t < NCHUNK) {
    int n = n0 + t;
    float mx = means[3 * n], my = means[3 * n + 1], mz = means[3 * n + 2];
    float scl = fmaxf((scales[3 * n] + scales[3 * n + 1] + scales[3 * n + 2]) * (1.0f / 3.0f), 1e-4f);
    float op = opac[n];
    float rzs = 1.0f / (fabsf(mz) + 1.0f);
    float px = tanhf(mx * rzs);
    float py = tanhf(my * rzs);
    float sigma = fminf(fmaxf(scl * rzs, 0.02f), 0.5f);
    float inv_s = 1.0f / sigma;
    float K = -0.72134752044f * inv_s * inv_s;  // -0.5/ln2 * inv_s^2
    pxL[t] = px;
    pyL[t] = py;
    kL[t] = K;
    colL[t] = make_float4(op * colors[3 * n], op * colors[3 * n + 1],
                          op * colors[3 * n + 2], op);
  }
  __syncthreads();

  // --- tables into LDS ---
  {
    float ccol = -1.0f + COORD_STEP * (float)col;  // absolute column (R6 fix)
    int nl0 = rq * 32;  // wave-uniform
#pragma unroll 4
    for (int k = 0; k < 32; ++k) {
      int nl = nl0 + k;
      float dx = ccol - pxL[nl];
      exL[nl][lane] = exp2f(kL[nl] * dx * dx);
    }
    int rl = t & 31;
    int nlb = t >> 5;  // 0..7
    float crow = -1.0f + COORD_STEP * (float)((blockIdx.y << 5) + rl);
#pragma unroll 4
    for (int k = 0; k < 16; ++k) {
      int nl = nlb + (k << 3);
      float dy = crow - pyL[nl];
      eyL[nl][rl] = exp2f(kL[nl] * dy * dy);
    }
  }
  __syncthreads();

  // --- main contraction: LDS-only reads, named accumulators ---
  float4 a0 = make_float4(0.f, 0.f, 0.f, 0.f);
  float4 a1 = a0, a2 = a0, a3 = a0, a4 = a0, a5 = a0, a6 = a0, a7 = a0;
  const int ey0 = rq << 3;

#pragma unroll 2
  for (int i = 0; i < NCHUNK; ++i) {
    float ex = exL[i][lane];
    float e0 = eyL[i][ey0 + 0], e1 = eyL[i][ey0 + 1];
    float e2 = eyL[i][ey0 + 2], e3 = eyL[i][ey0 + 3];
    float e4 = eyL[i][ey0 + 4], e5 = eyL[i][ey0 + 5];
    float e6 = eyL[i][ey0 + 6], e7 = eyL[i][ey0 + 7];
    float4 cc = colL[i];
#define GS_ROW(A, E)                              \
    {                                             \
      float w = (E) * ex;                         \
      A.x = fmaf(w, cc.x, A.x);                   \
      A.y = fmaf(w, cc.y, A.y);                   \
      A.z = fmaf(w, cc.z, A.z);                   \
      A.w = fmaf(w, cc.w, A.w);                   \
    }
    GS_ROW(a0, e0)
    GS_ROW(a1, e1)
    GS_ROW(a2, e2)
    GS_ROW(a3, e3)
    GS_ROW(a4, e4)
    GS_ROW(a5, e5)
    GS_ROW(a6, e6)
    GS_ROW(a7, e7)
#undef GS_ROW
  }

  // --- epilogue: coalesced stores into this part's private planes ---
  float* pb = partials + (size_t)blockIdx.z * 4 * PIX + col;
#define GS_ST(A, R)                               \
  {                                               \
    int base = (row0 + (R)) * WW;                 \
    pb[0 * PIX + base] = A.x;                     \
    pb[1 * PIX + base] = A.y;                     \
    pb[2 * PIX + base] = A.z;                     \
    pb[3 * PIX + base] = A.w;                     \
  }
  GS_ST(a0, 0)
  GS_ST(a1, 1)
  GS_ST(a2, 2)
  GS_ST(a3, 3)
  GS_ST(a4, 4)
  GS_ST(a5, 5)
  GS_ST(a6, 6)
  GS_ST(a7, 7)
#undef GS_ST
}

// grid = (PIX/4/256, 3); each thread: one float4-group of one channel.
__global__ __launch_bounds__(256) void gs_finalize(
    const float4* __restrict__ partials4, float4* __restrict__ out4,
    int parts) {
  int g = blockIdx.x * 256 + threadIdx.x;  // 0..PIX/4-1
  int ch = blockIdx.y;                     // 0..2
  float nx = 0.f, ny = 0.f, nz = 0.f, nw = 0.f;
  float dx = 0.f, dy = 0.f, dz = 0.f, dw = 0.f;
  const float4* np = partials4 + (size_t)ch * (PIX / 4) + g;
  const float4* dp = partials4 + (size_t)3 * (PIX / 4) + g;
#pragma unroll 8
  for (int p = 0; p < parts; ++p) {
    float4 a = *np;
    float4 b = *dp;
    nx += a.x; ny += a.y; nz += a.z; nw += a.w;
    dx += b.x; dy += b.y; dz += b.z; dw += b.w;
    np += 4 * (PIX / 4);
    dp += 4 * (PIX / 4);
  }
  float4 o;
  o.x = fminf(fmaxf(nx / fmaxf(dx, 1e-5f), 0.0f), 1.0f);
  o.y = fminf(fmaxf(ny / fmaxf(dy, 1e-5f), 0.0f), 1.0f);
  o.z = fminf(fmaxf(nz / fmaxf(dz, 1e-5f), 0.0f), 1.0f);
  o.w = fminf(fmaxf(nw / fmaxf(dw, 1e-5f), 0.0f), 1.0f);
  out4[(size_t)ch * (PIX / 4) + g] = o;
}

extern "C" void kernel_launch(void* const* d_in, const int* in_sizes, int n_in,
                              void* d_out, int out_size, void* d_ws, size_t ws_size,
                              hipStream_t stream) {
  const float* means = (const float*)d_in[0];
  // d_in[1] = quats (unused by reference)
  const float* scales = (const float*)d_in[2];
  const float* opac = (const float*)d_in[3];
  const float* colors = (const float*)d_in[4];
  float* out = (float*)d_out;
  int N = in_sizes[0] / 3;  // 2048

  int parts = N / NCHUNK;  // 16 for N=2048
  // Workspace: partials [parts][4][PIX] float (16 MB for N=2048).
  float* partials = (float*)d_ws;

  gs_accum<<<dim3(WW / 64, HH / 32, parts), 256, 0, stream>>>(
      means, scales, opac, colors, partials);
  gs_finalize<<<dim3(PIX / 4 / 256, 3), 256, 0, stream>>>(
      (const float4*)partials, (float4*)out, parts);
}